// Round 1
// baseline (269.668 us; speedup 1.0000x reference)
//
#include <hip/hip_runtime.h>

// Embedding gather: out[row, :] = weight[input[row], :]
// rows = 2048*8 = 16384, EMSIZE = 1024 fp32 (4 KB/row).
// One 256-thread block per row; each thread copies one float4.
// Fully coalesced read (contiguous 4 KB row) and write.

constexpr int EMSIZE       = 1024;
constexpr int VEC_PER_ROW  = EMSIZE / 4;   // 256 float4 per row

__global__ __launch_bounds__(256)
void EmbeddingMul_73564199845928_kernel(const int* __restrict__ idx,
                                        const float4* __restrict__ w,
                                        float4* __restrict__ out) {
    const int g   = blockIdx.x * 256 + threadIdx.x;   // global float4 id
    const int row = g >> 8;                           // 256 float4 per row
    const int col = g & (VEC_PER_ROW - 1);
    const int token = idx[row];                       // block-uniform broadcast
    out[g] = w[token * VEC_PER_ROW + col];
}

extern "C" void kernel_launch(void* const* d_in, const int* in_sizes, int n_in,
                              void* d_out, int out_size, void* d_ws, size_t ws_size,
                              hipStream_t stream) {
    const int*    idx = (const int*)d_in[0];
    const float4* w   = (const float4*)d_in[1];
    float4*       out = (float4*)d_out;

    const int total_vec = out_size / 4;          // 16,777,216 / 4 = 4,194,304
    const int blocks    = total_vec / 256;       // 16384 (one block per row)

    EmbeddingMul_73564199845928_kernel<<<blocks, 256, 0, stream>>>(idx, w, out);
}